// Round 2
// baseline (5974.285 us; speedup 1.0000x reference)
//
#include <hip/hip_runtime.h>
#include <math.h>

#define NB 16
#define P 1024
#define EPSV 1e-3f
#define INV_EPS 1000.0f
#define LOGEPS 1e-8f
#define ITERS 100
#define NBLK 256

// online LSE step: (m,s) <- (m,s) ⊕ point t   [1 exp, branchless]
__device__ __forceinline__ void olse(float& m, float& s, float t) {
  float e = __expf(-fabsf(t - m) * INV_EPS);
  bool gt = t > m;
  s = gt ? __fmaf_rn(s, e, 1.0f) : (s + e);
  m = gt ? t : m;
}

// combine two (m,s) states  [1 exp, branchless]
__device__ __forceinline__ void comb(float& m, float& s, float mo, float so) {
  float e = __expf(-fabsf(mo - m) * INV_EPS);
  bool gt = mo > m;
  s = gt ? __fmaf_rn(s, e, so) : __fmaf_rn(so, e, s);
  m = gt ? mo : m;
}

__global__ void __launch_bounds__(1024) sink_k(
    const float* __restrict__ C, const float* __restrict__ mu,
    const float* __restrict__ nu, float* __restrict__ out,
    float* __restrict__ pmbuf, float* __restrict__ psbuf,
    int* __restrict__ bar) {
  const int tid = threadIdx.x;
  const int blk = blockIdx.x;
  // XCD-local batch placement: blocks with same blk%8 share an XCD (round-robin
  // heuristic); batch n's 16 blocks then share one XCD's L2 for partial reads.
  const int xcd = blk & 7;
  const int j = blk >> 3;            // 0..31
  const int n = xcd * 2 + (j >> 4);  // batch
  const int rb = j & 15;             // 64-row stripe within batch
  const int wv = tid >> 6, ln = tid & 63;
  const int r0 = rb * 64 + wv * 4;   // this wave's 4 rows
  const int c0 = ln * 16;            // this lane's 16 cols

  __shared__ float msh[8 * 16 * 64];   // cross-wave tree buffers (32 KB)
  __shared__ float ssh[8 * 16 * 64];   // 32 KB
  __shared__ float vsh[P];             // v, stored as vsh[k*64+ln] = v[ln*16+k]
  __shared__ float red[16];

  // ---- load C tile into registers: 4 rows x 16 cols (64 VGPRs) ----
  float Creg[4][16];
  const float* Cn = C + (size_t)n * P * P;
#pragma unroll
  for (int r = 0; r < 4; ++r) {
#pragma unroll
    for (int k = 0; k < 16; k += 4) {
      float4 c4 = *(const float4*)(Cn + (size_t)(r0 + r) * P + c0 + k);
      Creg[r][k] = c4.x; Creg[r][k + 1] = c4.y;
      Creg[r][k + 2] = c4.z; Creg[r][k + 3] = c4.w;
    }
  }
  float elmu[4];
#pragma unroll
  for (int r = 0; r < 4; ++r) elmu[r] = EPSV * __logf(mu[n * P + r0 + r] + LOGEPS);
  const int cv = ln * 16 + wv;  // column this thread v-combines (transpose map)
  const float elnu_cv = EPSV * __logf(nu[n * P + cv] + LOGEPS);

  float u[4] = {1.0f, 1.0f, 1.0f, 1.0f};

  for (int it = 0; it < ITERS; ++it) {
    // ---- column-partial LSE over this wave's 4 rows, 16 cols ----
    float mc[16], sc[16];
#pragma unroll
    for (int k = 0; k < 16; ++k) { mc[k] = u[0] - Creg[0][k]; sc[k] = 1.0f; }
#pragma unroll
    for (int r = 1; r < 4; ++r)
#pragma unroll
      for (int k = 0; k < 16; ++k) olse(mc[k], sc[k], u[r] - Creg[r][k]);

    // ---- cross-wave tree combine 16 -> 1 (bank-conflict-free layout) ----
    for (int half = 8; half >= 1; half >>= 1) {
      __syncthreads();
      if (wv >= half && wv < 2 * half) {
        int base = (wv - half) * 1024;
#pragma unroll
        for (int k = 0; k < 16; ++k) {
          msh[base + k * 64 + ln] = mc[k];
          ssh[base + k * 64 + ln] = sc[k];
        }
      }
      __syncthreads();
      if (wv < half) {
        int base = wv * 1024;
#pragma unroll
        for (int k = 0; k < 16; ++k)
          comb(mc[k], sc[k], msh[base + k * 64 + ln], ssh[base + k * 64 + ln]);
      }
    }
    // wave 0 holds block-level (m,s) per col -> write partials (double-buffered)
    size_t pbase = (size_t)(it & 1) * (NB * 16 * P) + (size_t)(n * 16 + rb) * P;
    if (wv == 0) {
#pragma unroll
      for (int k = 0; k < 16; k += 4) {
        *(float4*)(pmbuf + pbase + c0 + k) = make_float4(mc[k], mc[k+1], mc[k+2], mc[k+3]);
        *(float4*)(psbuf + pbase + c0 + k) = make_float4(sc[k], sc[k+1], sc[k+2], sc[k+3]);
      }
    }

    // ---- grid barrier (monotonic counter; double-buffer makes 1/iter safe) ----
    __syncthreads();
    if (tid == 0) {
      __threadfence();
      atomicAdd(bar, 1);
      const int target = (it + 1) * NBLK;
      while (__hip_atomic_load(bar, __ATOMIC_RELAXED, __HIP_MEMORY_SCOPE_AGENT) < target)
        __builtin_amdgcn_s_sleep(2);
      __threadfence();
    }
    __syncthreads();

    // ---- v combine: thread (wv,ln) combines col cv over 16 stripe-partials ----
    const float* pmb = pmbuf + (size_t)(it & 1) * (NB * 16 * P) + (size_t)n * 16 * P;
    const float* psb = psbuf + (size_t)(it & 1) * (NB * 16 * P) + (size_t)n * 16 * P;
    float M = pmb[cv], S = psb[cv];
#pragma unroll
    for (int r2 = 1; r2 < 16; ++r2) comb(M, S, pmb[r2 * P + cv], psb[r2 * P + cv]);
    vsh[wv * 64 + ln] = elnu_cv - M - EPSV * __logf(S);
    __syncthreads();

    // ---- row phase: local LSE over 16 cols + 64-lane butterfly ----
    float vreg[16];
#pragma unroll
    for (int k = 0; k < 16; ++k) vreg[k] = vsh[k * 64 + ln];
#pragma unroll
    for (int r = 0; r < 4; ++r) {
      float mr = vreg[0] - Creg[r][0], sr = 1.0f;
#pragma unroll
      for (int k = 1; k < 16; ++k) olse(mr, sr, vreg[k] - Creg[r][k]);
#pragma unroll
      for (int off = 1; off < 64; off <<= 1) {
        float mo = __shfl_xor(mr, off);
        float so = __shfl_xor(sr, off);
        comb(mr, sr, mo, so);
      }
      u[r] = elmu[r] - mr - EPSV * __logf(sr);
    }
  }

  // ---- epilogue: pi = exp((u+v-C)/eps), cost = sum(pi*C) ----
  float acc = 0.0f;
  float* pi = out + 16 + (size_t)n * P * P;
#pragma unroll
  for (int r = 0; r < 4; ++r) {
    float* pr = pi + (size_t)(r0 + r) * P + c0;
#pragma unroll
    for (int k = 0; k < 16; k += 4) {
      float4 pv;
      pv.x = __expf((u[r] + vsh[(k + 0) * 64 + ln] - Creg[r][k + 0]) * INV_EPS);
      pv.y = __expf((u[r] + vsh[(k + 1) * 64 + ln] - Creg[r][k + 1]) * INV_EPS);
      pv.z = __expf((u[r] + vsh[(k + 2) * 64 + ln] - Creg[r][k + 2]) * INV_EPS);
      pv.w = __expf((u[r] + vsh[(k + 3) * 64 + ln] - Creg[r][k + 3]) * INV_EPS);
      *(float4*)(pr + k) = pv;
      acc = __fmaf_rn(pv.x, Creg[r][k + 0], acc);
      acc = __fmaf_rn(pv.y, Creg[r][k + 1], acc);
      acc = __fmaf_rn(pv.z, Creg[r][k + 2], acc);
      acc = __fmaf_rn(pv.w, Creg[r][k + 3], acc);
    }
  }
#pragma unroll
  for (int off = 1; off < 64; off <<= 1) acc += __shfl_xor(acc, off);
  __syncthreads();
  if (ln == 0) red[wv] = acc;
  __syncthreads();
  if (tid == 0) {
    float t = 0.0f;
#pragma unroll
    for (int w = 0; w < 16; ++w) t += red[w];
    atomicAdd(out + n, t);
  }
}

extern "C" void kernel_launch(void* const* d_in, const int* in_sizes, int n_in,
                              void* d_out, int out_size, void* d_ws, size_t ws_size,
                              hipStream_t stream) {
  const float* mu = (const float*)d_in[0];
  const float* nu = (const float*)d_in[1];
  const float* C  = (const float*)d_in[2];
  float* out = (float*)d_out;
  float* ws = (float*)d_ws;

  float* pm = ws;                          // 2 * NB*16*P floats (2 MB)
  float* ps = ws + 2 * NB * 16 * P;        // 2 MB
  int* bar  = (int*)(ws + 4 * NB * 16 * P);

  hipMemsetAsync(out, 0, NB * sizeof(float), stream);   // cost accumulators
  hipMemsetAsync(bar, 0, sizeof(int), stream);          // barrier counter

  void* args[] = {(void*)&C, (void*)&mu, (void*)&nu, (void*)&out,
                  (void*)&pm, (void*)&ps, (void*)&bar};
  hipLaunchCooperativeKernel((const void*)sink_k, dim3(NBLK), dim3(1024),
                             args, 0, stream);
}

// Round 3
// 5348.259 us; speedup vs baseline: 1.1171x; 1.1171x over previous
//
#include <hip/hip_runtime.h>
#include <math.h>

#define NB 16
#define P 1024
#define EPSV 1e-3f
#define INV_EPS 1000.0f
#define LOGEPS 1e-8f
#define ITERS 100
#define NBLK 256
#define S1 (NB * 16 * P)   // one partial buffer: 262144 floats (1 MB)

// online LSE step: (m,s) <- (m,s) ⊕ point t   [1 exp, branchless]
__device__ __forceinline__ void olse(float& m, float& s, float t) {
  float e = __expf(-fabsf(t - m) * INV_EPS);
  bool gt = t > m;
  s = gt ? __fmaf_rn(s, e, 1.0f) : (s + e);
  m = gt ? t : m;
}

// combine two (m,s) states  [1 exp, branchless]
__device__ __forceinline__ void comb(float& m, float& s, float mo, float so) {
  float e = __expf(-fabsf(mo - m) * INV_EPS);
  bool gt = mo > m;
  s = gt ? __fmaf_rn(s, e, so) : __fmaf_rn(so, e, s);
  m = gt ? mo : m;
}

// block = (batch n, 64-row stripe). wave wv owns rows r0..r0+3; lane ln owns
// cols ln*16..ln*16+15. C tile register-resident: 64 VGPRs/thread, read once.
// VGPR cap 128 via launch_bounds(1024,4): 16 waves/CU = 1 block/CU.
__global__ void __launch_bounds__(1024, 4) sink_k(
    const float* __restrict__ C, const float* __restrict__ mu,
    const float* __restrict__ nu, float* __restrict__ out,
    float* __restrict__ pmT, float* __restrict__ psT,
    int* __restrict__ bar) {
  const int tid = threadIdx.x;
  const int blk = blockIdx.x;
  // batch n's 16 stripe-blocks share an XCD (blk%8 round-robin heuristic)
  const int n = (blk & 7) * 2 + ((blk >> 3) >> 4);
  const int rb = (blk >> 3) & 15;
  const int wv = tid >> 6, ln = tid & 63;
  const int r0 = rb * 64 + wv * 4;
  const int c0 = ln * 16;

  // LDS slot s = k*64 + ln  <->  column c = ln*16 + k  (conflict-free both ways)
  __shared__ float msh[16 * 1024];  // 64 KB: [writer_wave][k*64+ln]
  __shared__ float ssh[16 * 1024];  // 64 KB
  __shared__ float vsh[P];          // vsh[k*64+ln] = v[ln*16+k]
  __shared__ float red[16];

  // ---- load C tile into registers (the only full read of C) ----
  float Creg[4][16];
  const float* Cn = C + (size_t)n * P * P;
#pragma unroll
  for (int r = 0; r < 4; ++r) {
#pragma unroll
    for (int k = 0; k < 16; k += 4) {
      float4 c4 = *(const float4*)(Cn + (size_t)(r0 + r) * P + c0 + k);
      Creg[r][k] = c4.x; Creg[r][k + 1] = c4.y;
      Creg[r][k + 2] = c4.z; Creg[r][k + 3] = c4.w;
    }
  }
  float elmu[4];
#pragma unroll
  for (int r = 0; r < 4; ++r) elmu[r] = EPSV * __logf(mu[n * P + r0 + r] + LOGEPS);
  const int cv = (tid & 63) * 16 + (tid >> 6);  // column this thread v-combines
  const float elnu_cv = EPSV * __logf(nu[n * P + cv] + LOGEPS);

  float u[4] = {1.0f, 1.0f, 1.0f, 1.0f};

  for (int it = 0; it < ITERS; ++it) {
    // ---- column phase: per-col (m,s) over this wave's 4 rows -> LDS ----
#pragma unroll
    for (int k = 0; k < 16; ++k) {
      float m = u[0] - Creg[0][k], s = 1.0f;
      olse(m, s, u[1] - Creg[1][k]);
      olse(m, s, u[2] - Creg[2][k]);
      olse(m, s, u[3] - Creg[3][k]);
      msh[wv * 1024 + k * 64 + ln] = m;
      ssh[wv * 1024 + k * 64 + ln] = s;
    }
    __syncthreads();
    // ---- single-level combine: thread tid combines slot tid over 16 waves ----
    float M = msh[tid], S = ssh[tid];
#pragma unroll
    for (int w = 1; w < 16; ++w) comb(M, S, msh[w * 1024 + tid], ssh[w * 1024 + tid]);
    // write block partial for col cv, stripe rb (transposed: [col][stripe])
    size_t pb = (size_t)(it & 1) * S1 + (size_t)n * 16 * P + (size_t)cv * 16 + rb;
    pmT[pb] = M;
    psT[pb] = S;

    // ---- grid barrier (monotonic counter; double-buffer -> 1/iter safe) ----
    __syncthreads();
    if (tid == 0) {
      __threadfence();
      atomicAdd(bar, 1);
      const int target = (it + 1) * NBLK;
      while (__hip_atomic_load(bar, __ATOMIC_RELAXED, __HIP_MEMORY_SCOPE_AGENT) < target)
        __builtin_amdgcn_s_sleep(2);
      __threadfence();
    }
    __syncthreads();

    // ---- v combine: 16 stripes for col cv, contiguous float4 reads ----
    {
      const float* pm = pmT + (size_t)(it & 1) * S1 + (size_t)n * 16 * P + (size_t)cv * 16;
      const float* ps = psT + (size_t)(it & 1) * S1 + (size_t)n * 16 * P + (size_t)cv * 16;
      float4 m4[4], s4[4];
#pragma unroll
      for (int q = 0; q < 4; ++q) {
        m4[q] = *(const float4*)(pm + q * 4);
        s4[q] = *(const float4*)(ps + q * 4);
      }
      float M2 = m4[0].x, S2 = s4[0].x;
      comb(M2, S2, m4[0].y, s4[0].y); comb(M2, S2, m4[0].z, s4[0].z);
      comb(M2, S2, m4[0].w, s4[0].w);
#pragma unroll
      for (int q = 1; q < 4; ++q) {
        comb(M2, S2, m4[q].x, s4[q].x); comb(M2, S2, m4[q].y, s4[q].y);
        comb(M2, S2, m4[q].z, s4[q].z); comb(M2, S2, m4[q].w, s4[q].w);
      }
      vsh[tid] = elnu_cv - M2 - EPSV * __logf(S2);  // slot tid <-> col cv
    }
    __syncthreads();

    // ---- row phase: stream v from LDS, 4-row online LSE + 64-lane butterfly ----
    float mr[4], sr[4];
    {
      float vk = vsh[ln];  // k=0
#pragma unroll
      for (int r = 0; r < 4; ++r) { mr[r] = vk - Creg[r][0]; sr[r] = 1.0f; }
    }
#pragma unroll
    for (int k = 1; k < 16; ++k) {
      float vk = vsh[k * 64 + ln];
#pragma unroll
      for (int r = 0; r < 4; ++r) olse(mr[r], sr[r], vk - Creg[r][k]);
    }
#pragma unroll
    for (int r = 0; r < 4; ++r) {
#pragma unroll
      for (int off = 1; off < 64; off <<= 1) {
        float mo = __shfl_xor(mr[r], off);
        float so = __shfl_xor(sr[r], off);
        comb(mr[r], sr[r], mo, so);
      }
      u[r] = elmu[r] - mr[r] - EPSV * __logf(sr[r]);
    }
  }

  // ---- epilogue: pi = exp((u+v-C)/eps), cost = sum(pi*C) ----
  float acc = 0.0f;
  float* pi = out + 16 + (size_t)n * P * P;
#pragma unroll
  for (int r = 0; r < 4; ++r) {
    float* pr = pi + (size_t)(r0 + r) * P + c0;
#pragma unroll
    for (int k = 0; k < 16; k += 4) {
      float4 pv;
      pv.x = __expf((u[r] + vsh[(k + 0) * 64 + ln] - Creg[r][k + 0]) * INV_EPS);
      pv.y = __expf((u[r] + vsh[(k + 1) * 64 + ln] - Creg[r][k + 1]) * INV_EPS);
      pv.z = __expf((u[r] + vsh[(k + 2) * 64 + ln] - Creg[r][k + 2]) * INV_EPS);
      pv.w = __expf((u[r] + vsh[(k + 3) * 64 + ln] - Creg[r][k + 3]) * INV_EPS);
      *(float4*)(pr + k) = pv;
      acc = __fmaf_rn(pv.x, Creg[r][k + 0], acc);
      acc = __fmaf_rn(pv.y, Creg[r][k + 1], acc);
      acc = __fmaf_rn(pv.z, Creg[r][k + 2], acc);
      acc = __fmaf_rn(pv.w, Creg[r][k + 3], acc);
    }
  }
#pragma unroll
  for (int off = 1; off < 64; off <<= 1) acc += __shfl_xor(acc, off);
  __syncthreads();
  if (ln == 0) red[wv] = acc;
  __syncthreads();
  if (tid == 0) {
    float t = 0.0f;
#pragma unroll
    for (int w = 0; w < 16; ++w) t += red[w];
    atomicAdd(out + n, t);
  }
}

extern "C" void kernel_launch(void* const* d_in, const int* in_sizes, int n_in,
                              void* d_out, int out_size, void* d_ws, size_t ws_size,
                              hipStream_t stream) {
  const float* mu = (const float*)d_in[0];
  const float* nu = (const float*)d_in[1];
  const float* C  = (const float*)d_in[2];
  float* out = (float*)d_out;
  float* ws = (float*)d_ws;

  float* pmT = ws;                 // 2*S1 floats (2 MB, double-buffered)
  float* psT = ws + 2 * S1;        // 2*S1 floats
  int* bar   = (int*)(ws + 4 * S1);

  hipMemsetAsync(out, 0, NB * sizeof(float), stream);  // cost accumulators
  hipMemsetAsync(bar, 0, sizeof(int), stream);         // barrier counter

  void* args[] = {(void*)&C, (void*)&mu, (void*)&nu, (void*)&out,
                  (void*)&pmT, (void*)&psT, (void*)&bar};
  hipLaunchCooperativeKernel((const void*)sink_k, dim3(NBLK), dim3(1024),
                             args, 0, stream);
}

// Round 4
// 4186.074 us; speedup vs baseline: 1.4272x; 1.2776x over previous
//
#include <hip/hip_runtime.h>
#include <math.h>

#define NB 16
#define P 1024
#define EPSV 1e-3f
#define INV_EPS 1000.0f
#define LOGEPS 1e-8f
#define ITERS 100
#define NBLK 256
#define SPB (NB * P * 16)   // psum floats per parity (1 MB)

// Persistent cooperative kernel. Block = (batch n, 16-row... 64-row stripe rb).
// Wave wv owns rows r0..r0+3 (all 1024 cols); lane ln owns cols ln*16..+15.
// E = exp(-C/eps) register-resident: 64 VGPRs/thread, computed once.
// waves_per_eu(4,4) pins the register budget at 128 (16 waves = 1 block/CU).
__global__ void __launch_bounds__(1024)
__attribute__((amdgpu_waves_per_eu(4, 4)))
sink_k(const float* __restrict__ C, const float* __restrict__ mu,
       const float* __restrict__ nu, float* __restrict__ out,
       float* __restrict__ psum, float* __restrict__ pmax,
       int* __restrict__ bar) {
  const int tid = threadIdx.x;
  const int blk = blockIdx.x;
  // batch's 16 blocks grouped on 2 XCDs (blk%8 round-robin heuristic)
  const int n = (blk & 7) * 2 + ((blk >> 3) >> 4);
  const int rb = (blk >> 3) & 15;
  const int wv = tid >> 6, ln = tid & 63;
  const int r0 = rb * 64 + wv * 4;
  const int c0 = ln * 16;

  __shared__ float ssum[P];   // column partial sums (ds_add_f32 target)
  __shared__ float vsh[P];    // v, slot k*64+ln <-> col ln*16+k
  __shared__ float bsh[P];    // b = exp((v-V)/eps), same slot map
  __shared__ float redA[16];
  __shared__ float redB[16];

  // ---- E tile into registers (only full read of C until epilogue) ----
  float E[4][16];
  const float* Cn = C + (size_t)n * P * P;
#pragma unroll
  for (int r = 0; r < 4; ++r) {
#pragma unroll
    for (int k = 0; k < 16; k += 4) {
      float4 c4 = *(const float4*)(Cn + (size_t)(r0 + r) * P + c0 + k);
      E[r][k]     = __expf(-c4.x * INV_EPS);
      E[r][k + 1] = __expf(-c4.y * INV_EPS);
      E[r][k + 2] = __expf(-c4.z * INV_EPS);
      E[r][k + 3] = __expf(-c4.w * INV_EPS);
    }
  }
  float elmu[4];
#pragma unroll
  for (int r = 0; r < 4; ++r) elmu[r] = EPSV * __logf(mu[n * P + r0 + r] + LOGEPS);
  const int cv = ln * 16 + wv;  // column owned for combine (slot(cv) == tid)
  const float elnu_cv = EPSV * __logf(nu[n * P + cv] + LOGEPS);

  float a[4] = {1.0f, 1.0f, 1.0f, 1.0f};  // u0=1, Mloc=1 -> a=1
  float u[4];
  float Mloc = 1.0f;
  int* bcnt = bar + n * 32;  // per-batch barrier counter (128-B spaced)
  ssum[tid] = 0.0f;
  __syncthreads();

  for (int it = 0; it < ITERS; ++it) {
    // ---- column phase: S_j += sum_r a[r]*E[r][j] via LDS float atomics ----
#pragma unroll
    for (int k = 0; k < 16; ++k) {
      float val = a[0] * E[0][k];
      val = __fmaf_rn(a[1], E[1][k], val);
      val = __fmaf_rn(a[2], E[2][k], val);
      val = __fmaf_rn(a[3], E[3][k], val);
      atomicAdd(&ssum[k * 64 + ln], val);
    }
    __syncthreads();
    // write stripe partial for col cv ([n][col][stripe] layout) + stripe max
    float Sv = ssum[tid];
    psum[(size_t)(it & 1) * SPB + (size_t)(n * P + cv) * 16 + rb] = Sv;
    if (tid == 0) pmax[(it & 1) * (NB * 16) + n * 16 + rb] = Mloc;
    ssum[tid] = 0.0f;  // re-zero for next iteration
    __syncthreads();

    // ---- per-batch grid barrier (16 blocks) ----
    if (tid == 0) {
      __threadfence();
      atomicAdd(bcnt, 1);
      const int target = (it + 1) * 16;
      while (__hip_atomic_load(bcnt, __ATOMIC_RELAXED, __HIP_MEMORY_SCOPE_AGENT) < target)
        __builtin_amdgcn_s_sleep(4);
      __threadfence();
    }
    __syncthreads();

    // ---- v-combine for col cv: S = sum_rb exp((M_rb-M*)/eps) * S_rb ----
    {
      const float* ps = psum + (size_t)(it & 1) * SPB + (size_t)(n * P + cv) * 16;
      const float* px = pmax + (it & 1) * (NB * 16) + n * 16;
      float4 m0 = *(const float4*)(px + 0);
      float4 m1 = *(const float4*)(px + 4);
      float4 m2 = *(const float4*)(px + 8);
      float4 m3 = *(const float4*)(px + 12);
      float Ms = fmaxf(fmaxf(fmaxf(m0.x, m0.y), fmaxf(m0.z, m0.w)),
                       fmaxf(fmaxf(m1.x, m1.y), fmaxf(m1.z, m1.w)));
      Ms = fmaxf(Ms, fmaxf(fmaxf(fmaxf(m2.x, m2.y), fmaxf(m2.z, m2.w)),
                           fmaxf(fmaxf(m3.x, m3.y), fmaxf(m3.z, m3.w))));
      float S = 0.0f;
      float4 s0 = *(const float4*)(ps + 0);
      float4 s1 = *(const float4*)(ps + 4);
      float4 s2 = *(const float4*)(ps + 8);
      float4 s3 = *(const float4*)(ps + 12);
      S = __fmaf_rn(__expf((m0.x - Ms) * INV_EPS), s0.x, S);
      S = __fmaf_rn(__expf((m0.y - Ms) * INV_EPS), s0.y, S);
      S = __fmaf_rn(__expf((m0.z - Ms) * INV_EPS), s0.z, S);
      S = __fmaf_rn(__expf((m0.w - Ms) * INV_EPS), s0.w, S);
      S = __fmaf_rn(__expf((m1.x - Ms) * INV_EPS), s1.x, S);
      S = __fmaf_rn(__expf((m1.y - Ms) * INV_EPS), s1.y, S);
      S = __fmaf_rn(__expf((m1.z - Ms) * INV_EPS), s1.z, S);
      S = __fmaf_rn(__expf((m1.w - Ms) * INV_EPS), s1.w, S);
      S = __fmaf_rn(__expf((m2.x - Ms) * INV_EPS), s2.x, S);
      S = __fmaf_rn(__expf((m2.y - Ms) * INV_EPS), s2.y, S);
      S = __fmaf_rn(__expf((m2.z - Ms) * INV_EPS), s2.z, S);
      S = __fmaf_rn(__expf((m2.w - Ms) * INV_EPS), s2.w, S);
      S = __fmaf_rn(__expf((m3.x - Ms) * INV_EPS), s3.x, S);
      S = __fmaf_rn(__expf((m3.y - Ms) * INV_EPS), s3.y, S);
      S = __fmaf_rn(__expf((m3.z - Ms) * INV_EPS), s3.z, S);
      S = __fmaf_rn(__expf((m3.w - Ms) * INV_EPS), s3.w, S);
      float v_cv = elnu_cv - Ms - EPSV * __logf(S);
      vsh[tid] = v_cv;
      // V = max_j v_j (block-local; identical across blocks of batch)
      float mv = v_cv;
#pragma unroll
      for (int off = 1; off < 64; off <<= 1) mv = fmaxf(mv, __shfl_xor(mv, off));
      if (ln == 0) redA[wv] = mv;
      __syncthreads();
      float V = redA[0];
#pragma unroll
      for (int w = 1; w < 16; ++w) V = fmaxf(V, redA[w]);
      bsh[tid] = __expf((v_cv - V) * INV_EPS);
      __syncthreads();

      // ---- row phase: T_r = sum_j E[r][j]*b_j (block-local rows) ----
      float T[4] = {0.0f, 0.0f, 0.0f, 0.0f};
#pragma unroll
      for (int k = 0; k < 16; ++k) {
        float b = bsh[k * 64 + ln];
        T[0] = __fmaf_rn(E[0][k], b, T[0]);
        T[1] = __fmaf_rn(E[1][k], b, T[1]);
        T[2] = __fmaf_rn(E[2][k], b, T[2]);
        T[3] = __fmaf_rn(E[3][k], b, T[3]);
      }
#pragma unroll
      for (int off = 1; off < 64; off <<= 1) {
        T[0] += __shfl_xor(T[0], off);
        T[1] += __shfl_xor(T[1], off);
        T[2] += __shfl_xor(T[2], off);
        T[3] += __shfl_xor(T[3], off);
      }
      float Ml = -1e30f;
#pragma unroll
      for (int r = 0; r < 4; ++r) {
        u[r] = elmu[r] - V - EPSV * __logf(T[r]);
        Ml = fmaxf(Ml, u[r]);
      }
      if (ln == 0) redB[wv] = Ml;
      __syncthreads();
      Mloc = redB[0];
#pragma unroll
      for (int w = 1; w < 16; ++w) Mloc = fmaxf(Mloc, redB[w]);
#pragma unroll
      for (int r = 0; r < 4; ++r) a[r] = __expf((u[r] - Mloc) * INV_EPS);
      __syncthreads();  // protect redA/redB/bsh reuse next iteration
    }
  }

  // ---- epilogue: reload C, pi = exp((u+v-C)/eps), cost = sum(pi*C) ----
  float acc = 0.0f;
  float* pi = out + 16 + (size_t)n * P * P;
#pragma unroll
  for (int r = 0; r < 4; ++r) {
    const float* Cr = Cn + (size_t)(r0 + r) * P + c0;
    float* pr = pi + (size_t)(r0 + r) * P + c0;
#pragma unroll
    for (int k = 0; k < 16; k += 4) {
      float4 c4 = *(const float4*)(Cr + k);
      float4 pv;
      pv.x = __expf((u[r] + vsh[(k + 0) * 64 + ln] - c4.x) * INV_EPS);
      pv.y = __expf((u[r] + vsh[(k + 1) * 64 + ln] - c4.y) * INV_EPS);
      pv.z = __expf((u[r] + vsh[(k + 2) * 64 + ln] - c4.z) * INV_EPS);
      pv.w = __expf((u[r] + vsh[(k + 3) * 64 + ln] - c4.w) * INV_EPS);
      *(float4*)(pr + k) = pv;
      acc = __fmaf_rn(pv.x, c4.x, acc);
      acc = __fmaf_rn(pv.y, c4.y, acc);
      acc = __fmaf_rn(pv.z, c4.z, acc);
      acc = __fmaf_rn(pv.w, c4.w, acc);
    }
  }
#pragma unroll
  for (int off = 1; off < 64; off <<= 1) acc += __shfl_xor(acc, off);
  __syncthreads();
  if (ln == 0) redA[wv] = acc;
  __syncthreads();
  if (tid == 0) {
    float t = 0.0f;
#pragma unroll
    for (int w = 0; w < 16; ++w) t += redA[w];
    atomicAdd(out + n, t);
  }
}

extern "C" void kernel_launch(void* const* d_in, const int* in_sizes, int n_in,
                              void* d_out, int out_size, void* d_ws, size_t ws_size,
                              hipStream_t stream) {
  const float* mu = (const float*)d_in[0];
  const float* nu = (const float*)d_in[1];
  const float* C  = (const float*)d_in[2];
  float* out = (float*)d_out;
  float* ws = (float*)d_ws;

  float* psum = ws;                      // 2*SPB floats (2 MB, double-buffered)
  float* pmax = ws + 2 * SPB;            // 2*NB*16 floats
  int* bar    = (int*)(pmax + 2 * NB * 16);  // NB*32 ints (per-batch counters)

  hipMemsetAsync(out, 0, NB * sizeof(float), stream);   // cost accumulators
  hipMemsetAsync(bar, 0, NB * 32 * sizeof(int), stream);

  void* args[] = {(void*)&C, (void*)&mu, (void*)&nu, (void*)&out,
                  (void*)&psum, (void*)&pmax, (void*)&bar};
  hipLaunchCooperativeKernel((const void*)sink_k, dim3(NBLK), dim3(1024),
                             args, 0, stream);
}

// Round 5
// 3036.300 us; speedup vs baseline: 1.9676x; 1.3787x over previous
//
#include <hip/hip_runtime.h>
#include <math.h>

#define NB 16
#define P 1024
#define EPSV 1e-3f
#define INV_EPS 1000.0f
#define LOGEPS 1e-8f
#define ITERS 100
#define NBLK 256
#define SPB (NB * 16 * P)   // psum floats per parity: [n][stripe][slot]

// Relaxed agent-scope (cache-bypassing, coherent) accessors — no fences needed.
__device__ __forceinline__ void cstore(float* p, float v) {
  __hip_atomic_store(p, v, __ATOMIC_RELAXED, __HIP_MEMORY_SCOPE_AGENT);
}
__device__ __forceinline__ float cload(const float* p) {
  return __hip_atomic_load(p, __ATOMIC_RELAXED, __HIP_MEMORY_SCOPE_AGENT);
}

// Persistent cooperative kernel. Block = (batch n, 64-row stripe rb).
// Wave wv owns rows r0..r0+3; lane ln owns cols ln*16..+15.
// E = exp(-C/eps) register-resident (unified VGPR/AGPR file), computed once.
__global__ void __launch_bounds__(1024)
sink_k(const float* __restrict__ C, const float* __restrict__ mu,
       const float* __restrict__ nu, float* __restrict__ out,
       float* __restrict__ psum, float* __restrict__ pmax,
       int* __restrict__ bar) {
  const int tid = threadIdx.x;
  const int blk = blockIdx.x;
  // batch's 16 blocks share blk%8 -> same XCD under round-robin dispatch
  // (perf heuristic only; correctness never depends on it)
  const int n = (blk & 7) * 2 + ((blk >> 3) >> 4);
  const int rb = (blk >> 3) & 15;
  const int wv = tid >> 6, ln = tid & 63;
  const int r0 = rb * 64 + wv * 4;
  const int c0 = ln * 16;

  __shared__ float ssum[P];   // column partial sums (LDS atomic target), slot k*64+ln
  __shared__ float vsh[P];    // v, slot k*64+ln <-> col ln*16+k
  __shared__ float bsh[P];    // b = exp((v-V)/eps), same slot map
  __shared__ float redA[16];
  __shared__ float redB[16];

  // ---- E tile into registers (only full read of C until epilogue) ----
  float E[4][16];
  const float* Cn = C + (size_t)n * P * P;
#pragma unroll
  for (int r = 0; r < 4; ++r) {
#pragma unroll
    for (int k = 0; k < 16; k += 4) {
      float4 c4 = *(const float4*)(Cn + (size_t)(r0 + r) * P + c0 + k);
      E[r][k]     = __expf(-c4.x * INV_EPS);
      E[r][k + 1] = __expf(-c4.y * INV_EPS);
      E[r][k + 2] = __expf(-c4.z * INV_EPS);
      E[r][k + 3] = __expf(-c4.w * INV_EPS);
    }
  }
  float elmu[4];
#pragma unroll
  for (int r = 0; r < 4; ++r) elmu[r] = EPSV * __logf(mu[n * P + r0 + r] + LOGEPS);
  const int cv = ln * 16 + wv;  // column owned for combine (slot(cv) == tid)
  const float elnu_cv = EPSV * __logf(nu[n * P + cv] + LOGEPS);

  float a[4] = {1.0f, 1.0f, 1.0f, 1.0f};  // u0=1, Mloc=1 -> a=1
  float u[4];
  float Mloc = 1.0f;
  int* bcnt = bar + n * 32;  // per-batch barrier counter (128-B spaced)
  ssum[tid] = 0.0f;
  __syncthreads();

  for (int it = 0; it < ITERS; ++it) {
    // ---- column phase: S_j += sum_r a[r]*E[r][j] via LDS float atomics ----
#pragma unroll
    for (int k = 0; k < 16; ++k) {
      float val = a[0] * E[0][k];
      val = __fmaf_rn(a[1], E[1][k], val);
      val = __fmaf_rn(a[2], E[2][k], val);
      val = __fmaf_rn(a[3], E[3][k], val);
      atomicAdd(&ssum[k * 64 + ln], val);
    }
    __syncthreads();
    // publish stripe partial (slot-ordered -> coalesced) + stripe max shift
    float Sv = ssum[tid];
    cstore(&psum[(size_t)(it & 1) * SPB + (size_t)(n * 16 + rb) * P + tid], Sv);
    if (tid == 0) cstore(&pmax[(it & 1) * (NB * 16) + n * 16 + rb], Mloc);
    ssum[tid] = 0.0f;  // re-zero for next iteration
    // ensure this wave's write-through stores reached the coherent point
    asm volatile("s_waitcnt vmcnt(0)" ::: "memory");
    __syncthreads();   // all waves' stores complete

    // ---- per-batch barrier: relaxed counter, no cache flushes ----
    if (tid == 0) {
      __hip_atomic_fetch_add(bcnt, 1, __ATOMIC_RELAXED, __HIP_MEMORY_SCOPE_AGENT);
      const int target = (it + 1) * 16;
      while (__hip_atomic_load(bcnt, __ATOMIC_RELAXED, __HIP_MEMORY_SCOPE_AGENT) < target)
        __builtin_amdgcn_s_sleep(1);
    }
    __syncthreads();

    // ---- v-combine for col cv: S = sum_rb exp((M_rb-M*)/eps) * S_rb ----
    {
      const float* ps = psum + (size_t)(it & 1) * SPB + (size_t)n * 16 * P;
      const float* px = pmax + (it & 1) * (NB * 16) + n * 16;
      float mrb[16], srb[16];
#pragma unroll
      for (int q = 0; q < 16; ++q) mrb[q] = cload(px + q);
#pragma unroll
      for (int q = 0; q < 16; ++q) srb[q] = cload(ps + q * P + tid);
      float Ms = mrb[0];
#pragma unroll
      for (int q = 1; q < 16; ++q) Ms = fmaxf(Ms, mrb[q]);
      float S = 0.0f;
#pragma unroll
      for (int q = 0; q < 16; ++q)
        S = __fmaf_rn(__expf((mrb[q] - Ms) * INV_EPS), srb[q], S);
      float v_cv = elnu_cv - Ms - EPSV * __logf(S);
      vsh[tid] = v_cv;
      // V = max_j v_j (block-local; identical across a batch's blocks)
      float mv = v_cv;
#pragma unroll
      for (int off = 1; off < 64; off <<= 1) mv = fmaxf(mv, __shfl_xor(mv, off));
      if (ln == 0) redA[wv] = mv;
      __syncthreads();
      float V = redA[0];
#pragma unroll
      for (int w = 1; w < 16; ++w) V = fmaxf(V, redA[w]);
      bsh[tid] = __expf((v_cv - V) * INV_EPS);
      __syncthreads();

      // ---- row phase: T_r = sum_j E[r][j]*b_j (block-local rows) ----
      float T[4] = {0.0f, 0.0f, 0.0f, 0.0f};
#pragma unroll
      for (int k = 0; k < 16; ++k) {
        float b = bsh[k * 64 + ln];
        T[0] = __fmaf_rn(E[0][k], b, T[0]);
        T[1] = __fmaf_rn(E[1][k], b, T[1]);
        T[2] = __fmaf_rn(E[2][k], b, T[2]);
        T[3] = __fmaf_rn(E[3][k], b, T[3]);
      }
#pragma unroll
      for (int off = 1; off < 64; off <<= 1) {
        T[0] += __shfl_xor(T[0], off);
        T[1] += __shfl_xor(T[1], off);
        T[2] += __shfl_xor(T[2], off);
        T[3] += __shfl_xor(T[3], off);
      }
      float Ml = -1e30f;
#pragma unroll
      for (int r = 0; r < 4; ++r) {
        u[r] = elmu[r] - V - EPSV * __logf(T[r]);
        Ml = fmaxf(Ml, u[r]);
      }
      if (ln == 0) redB[wv] = Ml;
      __syncthreads();
      Mloc = redB[0];
#pragma unroll
      for (int w = 1; w < 16; ++w) Mloc = fmaxf(Mloc, redB[w]);
#pragma unroll
      for (int r = 0; r < 4; ++r) a[r] = __expf((u[r] - Mloc) * INV_EPS);
      __syncthreads();  // protect redA/redB/bsh reuse next iteration
    }
  }

  // ---- epilogue: reload C, pi = exp((u+v-C)/eps), cost = sum(pi*C) ----
  float acc = 0.0f;
  float* pi = out + 16 + (size_t)n * P * P;
#pragma unroll
  for (int r = 0; r < 4; ++r) {
    const float* Cr = Cn + (size_t)(r0 + r) * P + c0;
    float* pr = pi + (size_t)(r0 + r) * P + c0;
#pragma unroll
    for (int k = 0; k < 16; k += 4) {
      float4 c4 = *(const float4*)(Cr + k);
      float4 pv;
      pv.x = __expf((u[r] + vsh[(k + 0) * 64 + ln] - c4.x) * INV_EPS);
      pv.y = __expf((u[r] + vsh[(k + 1) * 64 + ln] - c4.y) * INV_EPS);
      pv.z = __expf((u[r] + vsh[(k + 2) * 64 + ln] - c4.z) * INV_EPS);
      pv.w = __expf((u[r] + vsh[(k + 3) * 64 + ln] - c4.w) * INV_EPS);
      *(float4*)(pr + k) = pv;
      acc = __fmaf_rn(pv.x, c4.x, acc);
      acc = __fmaf_rn(pv.y, c4.y, acc);
      acc = __fmaf_rn(pv.z, c4.z, acc);
      acc = __fmaf_rn(pv.w, c4.w, acc);
    }
  }
#pragma unroll
  for (int off = 1; off < 64; off <<= 1) acc += __shfl_xor(acc, off);
  __syncthreads();
  if (ln == 0) redA[wv] = acc;
  __syncthreads();
  if (tid == 0) {
    float t = 0.0f;
#pragma unroll
    for (int w = 0; w < 16; ++w) t += redA[w];
    atomicAdd(out + n, t);
  }
}

extern "C" void kernel_launch(void* const* d_in, const int* in_sizes, int n_in,
                              void* d_out, int out_size, void* d_ws, size_t ws_size,
                              hipStream_t stream) {
  const float* mu = (const float*)d_in[0];
  const float* nu = (const float*)d_in[1];
  const float* C  = (const float*)d_in[2];
  float* out = (float*)d_out;
  float* ws = (float*)d_ws;

  float* psum = ws;                      // 2*SPB floats (2 MB, double-buffered)
  float* pmax = ws + 2 * SPB;            // 2*NB*16 floats
  int* bar    = (int*)(pmax + 2 * NB * 16);  // NB*32 ints (per-batch counters)

  hipMemsetAsync(out, 0, NB * sizeof(float), stream);   // cost accumulators
  hipMemsetAsync(bar, 0, NB * 32 * sizeof(int), stream);

  void* args[] = {(void*)&C, (void*)&mu, (void*)&nu, (void*)&out,
                  (void*)&psum, (void*)&pmax, (void*)&bar};
  hipLaunchCooperativeKernel((const void*)sink_k, dim3(NBLK), dim3(1024),
                             args, 0, stream);
}